// Round 10
// baseline (215.376 us; speedup 1.0000x reference)
//
#include <hip/hip_runtime.h>
#include <hip/hip_bf16.h>

#define D 128
#define CAT 640
#define BM 32
#define W1F_ELEMS 81920    // 20*8*64*8
#define W2F_ELEMS 16384    // 4*8*64*8

typedef __attribute__((ext_vector_type(8))) short bf16x8;
typedef __attribute__((ext_vector_type(4))) float f32x4;

static __device__ __forceinline__ unsigned short f32_to_bf16(float f) {
    unsigned u = __float_as_uint(f);
    unsigned r = u + 0x7FFFu + ((u >> 16) & 1u);   // RNE
    return (unsigned short)(r >> 16);
}

static __device__ __forceinline__ unsigned pack_bf16x2(float a, float b) {
    __hip_bfloat162 h = __float22bfloat162_rn(make_float2(a, b));  // v_cvt_pk_bf16_f32
    return *reinterpret_cast<unsigned*>(&h);
}

// async global->LDS, 16B per lane, wave-uniform LDS base + lane*16
static __device__ __forceinline__ void gload_lds16(const float* g, void* lds) {
    __builtin_amdgcn_global_load_lds(
        (const __attribute__((address_space(1))) void*)g,
        (__attribute__((address_space(3))) void*)lds, 16, 0, 0);
}

// Pack W1 [128][640] and W2 [128][128] (fp32, torch Linear [out,in]) into MFMA
// B-fragment order: (ks, j16, lane, e) = W[j16*16 + (lane&15)][ks*32 + (lane>>4)*8 + e]
__global__ void prep_frags(const float* __restrict__ W1, const float* __restrict__ W2,
                           unsigned short* __restrict__ W1f, unsigned short* __restrict__ W2f) {
    int f = blockIdx.x * 256 + threadIdx.x;
    if (f < W1F_ELEMS) {
        int e = f & 7, l = (f >> 3) & 63, j16 = (f >> 9) & 7, ks = f >> 12;
        int o = j16 * 16 + (l & 15);
        int k = ks * 32 + ((l >> 4) << 3) + e;
        W1f[f] = f32_to_bf16(W1[o * CAT + k]);
    } else if (f < W1F_ELEMS + W2F_ELEMS) {
        int f2 = f - W1F_ELEMS;
        int e = f2 & 7, l = (f2 >> 3) & 63, j16 = (f2 >> 9) & 7, ks = f2 >> 12;
        int o = j16 * 16 + (l & 15);
        int k = ks * 32 + ((l >> 4) << 3) + e;
        W2f[f2] = f32_to_bf16(W2[o * D + k]);
    }
}

// R10 = R7 (best measured, 192.6us) with EXACTLY ONE change: fragment-linear
// A staging. Chunk layout [m][ks][h] slots of 1KB, lane-linear 16B — the
// wave-uniform-base+lane*16 write of global_load_lds IS the MFMA fragment
// order, and every GEMM1 ds_read_b128 is contiguous (m134 conflict-free
// baseline). R7/R8's row-major XOR tile measured 1.15e7 conflict-cycles
// (8 lanes -> 8 distinct addrs in one 4-bank group on every A-read).
// Everything else is R7: inline W1 loads in COMPUTE (R9's W1-in-regs A/B'd
// worse), vmcnt(0)+barrier per chunk, 2x16KB double buffer, Hb aliased into
// buffer 1 for the epilogue, 4 blocks/CU.
__global__ __launch_bounds__(256, 4) void rowmlp_kernel(
    const float* __restrict__ x_rows, const int* __restrict__ seeds,
    const unsigned short* __restrict__ W1f, const float* __restrict__ b1,
    const unsigned short* __restrict__ W2f, const float* __restrict__ b2,
    float* __restrict__ out, int Nrows)
{
    __shared__ __align__(16) unsigned char Ab[2][16384];   // fragment-linear staging
    __shared__ int sseed[BM];

    const int tid = threadIdx.x;
    const int blk = blockIdx.x;
    const int w   = tid >> 6;    // wave 0..3
    const int l   = tid & 63;
    const int l15 = l & 15;
    const int lhi = l >> 4;

    if (tid < BM) sseed[tid] = seeds[blk * BM + tid];
    __syncthreads();

    // staging: wave w owns fragment-slots (m = w>>1, ks = (w&1)*2 + (t>>1), h = t&1).
    // lane l loads floats [ks*32 + lhi*8 + h*4, +4) of row seed[m*16 + l15] + j - 2.
    const int sb  = sseed[((w >> 1) << 4) + l15];
    const int ksb = (w & 1) * 2;

    const bf16x8* W1v = (const bf16x8*)W1f;
    const bf16x8* W2v = (const bf16x8*)W2f;

#define WAIT0 asm volatile("s_waitcnt vmcnt(0)" ::: "memory")
#define BAR   __builtin_amdgcn_s_barrier()

#define ISSUE(J, BUF)                                                          \
    {                                                                          \
        int idx = sb + (J) - 2;                                                \
        idx = idx < 0 ? 0 : (idx >= Nrows ? Nrows - 1 : idx);                  \
        const float* rp = x_rows + (size_t)idx * D + lhi * 8;                  \
        unsigned char* dst = Ab[BUF] + w * 4096;                               \
        gload_lds16(rp + (ksb + 0) * 32 + 0, dst + 0 * 1024);                  \
        gload_lds16(rp + (ksb + 0) * 32 + 4, dst + 1 * 1024);                  \
        gload_lds16(rp + (ksb + 1) * 32 + 0, dst + 2 * 1024);                  \
        gload_lds16(rp + (ksb + 1) * 32 + 4, dst + 3 * 1024);                  \
    }

#define COMPUTE(BUF, J)                                                        \
    {                                                                          \
        const float* fb = (const float*)Ab[BUF];                               \
        _Pragma("unroll")                                                      \
        for (int ks = 0; ks < 4; ++ks) {                                       \
            bf16x8 a[2];                                                       \
            _Pragma("unroll")                                                  \
            for (int m = 0; m < 2; ++m) {                                      \
                float4 q0 = *(const float4*)(fb + (m * 8 + ks * 2 + 0) * 256 + l * 4); \
                float4 q1 = *(const float4*)(fb + (m * 8 + ks * 2 + 1) * 256 + l * 4); \
                union { unsigned u[4]; bf16x8 v; } pk;                         \
                pk.u[0] = pack_bf16x2(q0.x, q0.y);                             \
                pk.u[1] = pack_bf16x2(q0.z, q0.w);                             \
                pk.u[2] = pack_bf16x2(q1.x, q1.y);                             \
                pk.u[3] = pack_bf16x2(q1.z, q1.w);                             \
                a[m] = pk.v;                                                   \
            }                                                                  \
            _Pragma("unroll")                                                  \
            for (int n = 0; n < 2; ++n) {                                      \
                bf16x8 b = W1v[(((J) * 4 + ks) * 8 + (w * 2 + n)) * 64 + l];   \
                _Pragma("unroll")                                              \
                for (int m = 0; m < 2; ++m)                                    \
                    acc[m][n] = __builtin_amdgcn_mfma_f32_16x16x32_bf16(       \
                        a[m], b, acc[m][n], 0, 0, 0);                          \
            }                                                                  \
        }                                                                      \
    }

    f32x4 acc[2][2] = {};

    // prologue
    ISSUE(0, 0)

    // j=0
    WAIT0; BAR;
    ISSUE(1, 1)
    COMPUTE(0, 0)
    // j=1
    WAIT0; BAR;
    ISSUE(2, 0)
    COMPUTE(1, 1)
    // j=2
    WAIT0; BAR;
    ISSUE(3, 1)
    COMPUTE(0, 2)
    // j=3
    WAIT0; BAR;
    ISSUE(4, 0)
    COMPUTE(1, 3)
    // j=4
    WAIT0; BAR;
    COMPUTE(0, 4)

    // ---- epilogue: bias + ReLU -> bf16 Hb aliased into Ab[1] (chunk 3's
    // buffer — all waves done with it; chunk-4 reads use Ab[0], disjoint).
    unsigned short (*Hb)[D] = (unsigned short (*)[D])Ab[1];
    #pragma unroll
    for (int n = 0; n < 2; ++n) {
        const int col = w * 32 + n * 16 + l15;
        const float bias = b1[col];
        #pragma unroll
        for (int m = 0; m < 2; ++m) {
            #pragma unroll
            for (int r = 0; r < 4; ++r) {
                float v = acc[m][n][r] + bias;
                v = v > 0.f ? v : 0.f;
                const int row = m * 16 + lhi * 4 + r;  // C/D: col=lane&15, row=(lane>>4)*4+reg
                Hb[row][col ^ ((row & 7) << 3)] = f32_to_bf16(v);
            }
        }
    }
    __syncthreads();

    // GEMM2: out = h @ W2^T  (M=32, N=32/wave, K=128)
    f32x4 acc2[2][2] = {};
    #pragma unroll
    for (int ks = 0; ks < 4; ++ks) {
        bf16x8 a2[2], bb[2];
        #pragma unroll
        for (int m = 0; m < 2; ++m) {
            const int row = m * 16 + l15;
            a2[m] = *(const bf16x8*)(&Hb[row][(ks * 32 + lhi * 8) ^ ((row & 7) << 3)]);
        }
        #pragma unroll
        for (int n = 0; n < 2; ++n) {
            const int j16 = w * 2 + n;
            bb[n] = W2v[(ks * 8 + j16) * 64 + l];
        }
        #pragma unroll
        for (int m = 0; m < 2; ++m)
            #pragma unroll
            for (int n = 0; n < 2; ++n)
                acc2[m][n] = __builtin_amdgcn_mfma_f32_16x16x32_bf16(a2[m], bb[n], acc2[m][n], 0, 0, 0);
    }

    // bias + fp32 store
    #pragma unroll
    for (int n = 0; n < 2; ++n) {
        const int col = w * 32 + n * 16 + l15;
        const float bias = b2[col];
        #pragma unroll
        for (int m = 0; m < 2; ++m) {
            #pragma unroll
            for (int r = 0; r < 4; ++r) {
                const int row = m * 16 + lhi * 4 + r;
                out[(size_t)(blk * BM + row) * D + col] = acc2[m][n][r] + bias;
            }
        }
    }
#undef ISSUE
#undef COMPUTE
#undef WAIT0
#undef BAR
}

extern "C" void kernel_launch(void* const* d_in, const int* in_sizes, int n_in,
                              void* d_out, int out_size, void* d_ws, size_t ws_size,
                              hipStream_t stream) {
    const float* x_rows = (const float*)d_in[0];
    const int*   seeds  = (const int*)d_in[1];
    const float* W1     = (const float*)d_in[2];
    const float* b1     = (const float*)d_in[3];
    const float* W2     = (const float*)d_in[4];
    const float* b2     = (const float*)d_in[5];
    float* out = (float*)d_out;

    int Nrows = in_sizes[0] / D;
    int B = in_sizes[1];

    unsigned short* W1f = (unsigned short*)d_ws;
    unsigned short* W2f = W1f + W1F_ELEMS;

    prep_frags<<<(W1F_ELEMS + W2F_ELEMS + 255) / 256, 256, 0, stream>>>(W1, W2, W1f, W2f);
    rowmlp_kernel<<<B / BM, 256, 0, stream>>>(x_rows, seeds, W1f, b1, W2f, b2, out, Nrows);
}

// Round 11
// 183.011 us; speedup vs baseline: 1.1768x; 1.1768x over previous
//
#include <hip/hip_runtime.h>
#include <hip/hip_bf16.h>

#define D 128
#define CAT 640
#define BM 32
#define W1F_ELEMS 81920    // 20*8*64*8
#define W2F_ELEMS 16384    // 4*8*64*8

typedef __attribute__((ext_vector_type(8))) short bf16x8;
typedef __attribute__((ext_vector_type(4))) float f32x4;

static __device__ __forceinline__ unsigned short f32_to_bf16(float f) {
    unsigned u = __float_as_uint(f);
    unsigned r = u + 0x7FFFu + ((u >> 16) & 1u);   // RNE
    return (unsigned short)(r >> 16);
}

static __device__ __forceinline__ unsigned pack_bf16x2(float a, float b) {
    __hip_bfloat162 h = __float22bfloat162_rn(make_float2(a, b));  // v_cvt_pk_bf16_f32
    return *reinterpret_cast<unsigned*>(&h);
}

// async global->LDS, 16B per lane, wave-uniform LDS base + lane*16
static __device__ __forceinline__ void gload_lds16(const float* g, void* lds) {
    __builtin_amdgcn_global_load_lds(
        (const __attribute__((address_space(1))) void*)g,
        (__attribute__((address_space(3))) void*)lds, 16, 0, 0);
}

// Pack W1 [128][640] and W2 [128][128] (fp32, torch Linear [out,in]) into MFMA
// B-fragment order: (ks, j16, lane, e) = W[j16*16 + (lane&15)][ks*32 + (lane>>4)*8 + e]
__global__ void prep_frags(const float* __restrict__ W1, const float* __restrict__ W2,
                           unsigned short* __restrict__ W1f, unsigned short* __restrict__ W2f) {
    int f = blockIdx.x * 256 + threadIdx.x;
    if (f < W1F_ELEMS) {
        int e = f & 7, l = (f >> 3) & 63, j16 = (f >> 9) & 7, ks = f >> 12;
        int o = j16 * 16 + (l & 15);
        int k = ks * 32 + ((l >> 4) << 3) + e;
        W1f[f] = f32_to_bf16(W1[o * CAT + k]);
    } else if (f < W1F_ELEMS + W2F_ELEMS) {
        int f2 = f - W1F_ELEMS;
        int e = f2 & 7, l = (f2 >> 3) & 63, j16 = (f2 >> 9) & 7, ks = f2 >> 12;
        int o = j16 * 16 + (l & 15);
        int k = ks * 32 + ((l >> 4) << 3) + e;
        W2f[f2] = f32_to_bf16(W2[o * D + k]);
    }
}

// R11 = R7 (best, 192.6us) + exactly one change: W1 fragments double-buffered
// in REGISTERS, loaded one chunk ahead. COMPUTE then contains zero vmem ops
// (MFMA + LDS only), so the MFMA stream never stalls mid-phase and the vmem
// queue at each phase top is just 4 gathers + 8 W1 L2-hits, drained by one
// vmcnt(0). A/B matrix: R10 showed scattered staging = +23us; R9 vs R10
// showed W1-in-regs = -7us on the scattered base; this is the missing cell
// (coalesced staging + W1-in-regs). Staging, barriers, epilogue = R7 verbatim
// (GEMM2 reuses acc to keep VGPR <= 128 for 4 blocks/CU).
__global__ __launch_bounds__(256, 4) void rowmlp_kernel(
    const float* __restrict__ x_rows, const int* __restrict__ seeds,
    const unsigned short* __restrict__ W1f, const float* __restrict__ b1,
    const unsigned short* __restrict__ W2f, const float* __restrict__ b2,
    float* __restrict__ out, int Nrows)
{
    __shared__ __align__(16) unsigned char smem[2][16384];
    __shared__ int sseed[BM];

    const int tid = threadIdx.x;
    const int blk = blockIdx.x;

    if (tid < BM) sseed[tid] = seeds[blk * BM + tid];
    __syncthreads();

    const int w   = tid >> 6;    // wave: stages rows 8w..8w+7; owns cols 32w..32w+31
    const int l   = tid & 63;
    const int l15 = l & 15;
    const int lhi = l >> 4;

    // staging geometry (R7): instr i covers rows 8w+2i, 8w+2i+1;
    // lane covers 16B chunk c=l&31 of its row; source chunk pre-swizzled c^(r&7).
    int sbase[4], scoff[4];
    #pragma unroll
    for (int i = 0; i < 4; ++i) {
        int r = 8 * w + 2 * i + (l >> 5);
        sbase[i] = sseed[r];
        scoff[i] = ((l & 31) ^ (r & 7)) << 2;   // float offset within row
    }

    const bf16x8* W1v = (const bf16x8*)W1f;
    const bf16x8* W2v = (const bf16x8*)W2f;

#define WAIT0 asm volatile("s_waitcnt vmcnt(0)" ::: "memory")
#define BAR   __builtin_amdgcn_s_barrier()

#define ISSUE(J)                                                               \
    {                                                                          \
        _Pragma("unroll")                                                      \
        for (int i = 0; i < 4; ++i) {                                          \
            int idx = sbase[i] + (J) - 2;                                      \
            idx = idx < 0 ? 0 : (idx >= Nrows ? Nrows - 1 : idx);              \
            gload_lds16(x_rows + (size_t)idx * D + scoff[i],                   \
                        (void*)(smem[(J) & 1] + w * 4096 + i * 1024));         \
        }                                                                      \
    }

#define LOADW1(J, RB)                                                          \
    {                                                                          \
        _Pragma("unroll")                                                      \
        for (int ks = 0; ks < 4; ++ks)                                         \
            _Pragma("unroll")                                                  \
            for (int n = 0; n < 2; ++n)                                        \
                w1r[RB][ks][n] = W1v[(((J) * 4 + ks) * 8 + (w * 2 + n)) * 64 + l]; \
    }

#define COMPUTE(BUF, RB)                                                       \
    {                                                                          \
        const float* buf = (const float*)smem[BUF];                            \
        _Pragma("unroll")                                                      \
        for (int ks = 0; ks < 4; ++ks) {                                       \
            bf16x8 a[2];                                                       \
            _Pragma("unroll")                                                  \
            for (int m = 0; m < 2; ++m) {                                      \
                const int r = m * 16 + l15;                                    \
                const int s = r & 7;                                           \
                const int cc = ks * 8 + lhi * 2;                               \
                float4 q0 = *(const float4*)(buf + r * 128 + (((cc) ^ s) << 2));     \
                float4 q1 = *(const float4*)(buf + r * 128 + (((cc + 1) ^ s) << 2)); \
                union { unsigned u[4]; bf16x8 v; } pk;                         \
                pk.u[0] = pack_bf16x2(q0.x, q0.y);                             \
                pk.u[1] = pack_bf16x2(q0.z, q0.w);                             \
                pk.u[2] = pack_bf16x2(q1.x, q1.y);                             \
                pk.u[3] = pack_bf16x2(q1.z, q1.w);                             \
                a[m] = pk.v;                                                   \
            }                                                                  \
            _Pragma("unroll")                                                  \
            for (int n = 0; n < 2; ++n)                                        \
                _Pragma("unroll")                                              \
                for (int m = 0; m < 2; ++m)                                    \
                    acc[m][n] = __builtin_amdgcn_mfma_f32_16x16x32_bf16(       \
                        a[m], w1r[RB][ks][n], acc[m][n], 0, 0, 0);             \
        }                                                                      \
    }

    bf16x8 w1r[2][4][2];
    f32x4 acc[2][2] = {};

    // prologue: gather chunk 0, W1 regs for chunk 0
    ISSUE(0)
    LOADW1(0, 0)

    // j=0
    WAIT0; BAR;
    ISSUE(1) LOADW1(1, 1)
    COMPUTE(0, 0)
    // j=1
    WAIT0; BAR;
    ISSUE(2) LOADW1(2, 0)
    COMPUTE(1, 1)
    // j=2
    WAIT0; BAR;
    ISSUE(3) LOADW1(3, 1)
    COMPUTE(0, 0)
    // j=3
    WAIT0; BAR;
    ISSUE(4) LOADW1(4, 0)
    COMPUTE(1, 1)
    // j=4
    WAIT0; BAR;
    COMPUTE(0, 0)

    // ---- epilogue (R7 verbatim): bias + ReLU -> bf16 Hb aliased into smem[1]
    // (chunk-3 buffer, all waves done with it; chunk-4 readers use smem[0]).
    unsigned short (*Hb)[D] = (unsigned short (*)[D])smem[1];
    #pragma unroll
    for (int n = 0; n < 2; ++n) {
        const int col = w * 32 + n * 16 + l15;
        const float bias = b1[col];
        #pragma unroll
        for (int m = 0; m < 2; ++m) {
            #pragma unroll
            for (int r = 0; r < 4; ++r) {
                float v = acc[m][n][r] + bias;
                v = v > 0.f ? v : 0.f;
                const int row = m * 16 + lhi * 4 + r;  // C/D: col=lane&15, row=(lane>>4)*4+reg
                Hb[row][col ^ ((row & 7) << 3)] = f32_to_bf16(v);
            }
        }
    }
    __syncthreads();

    // GEMM2: out = h @ W2^T  (M=32, N=32/wave, K=128) — reuse acc as accumulator
    #pragma unroll
    for (int m = 0; m < 2; ++m)
        #pragma unroll
        for (int n = 0; n < 2; ++n)
            acc[m][n] = (f32x4){0.f, 0.f, 0.f, 0.f};
    #pragma unroll
    for (int ks = 0; ks < 4; ++ks) {
        bf16x8 a2[2], bb[2];
        #pragma unroll
        for (int m = 0; m < 2; ++m) {
            const int row = m * 16 + l15;
            a2[m] = *(const bf16x8*)(&Hb[row][(ks * 32 + lhi * 8) ^ ((row & 7) << 3)]);
        }
        #pragma unroll
        for (int n = 0; n < 2; ++n) {
            const int j16 = w * 2 + n;
            bb[n] = W2v[(ks * 8 + j16) * 64 + l];
        }
        #pragma unroll
        for (int m = 0; m < 2; ++m)
            #pragma unroll
            for (int n = 0; n < 2; ++n)
                acc[m][n] = __builtin_amdgcn_mfma_f32_16x16x32_bf16(a2[m], bb[n], acc[m][n], 0, 0, 0);
    }

    // bias + fp32 store
    #pragma unroll
    for (int n = 0; n < 2; ++n) {
        const int col = w * 32 + n * 16 + l15;
        const float bias = b2[col];
        #pragma unroll
        for (int m = 0; m < 2; ++m) {
            #pragma unroll
            for (int r = 0; r < 4; ++r) {
                const int row = m * 16 + lhi * 4 + r;
                out[(size_t)(blk * BM + row) * D + col] = acc[m][n][r] + bias;
            }
        }
    }
#undef ISSUE
#undef LOADW1
#undef COMPUTE
#undef WAIT0
#undef BAR
}

extern "C" void kernel_launch(void* const* d_in, const int* in_sizes, int n_in,
                              void* d_out, int out_size, void* d_ws, size_t ws_size,
                              hipStream_t stream) {
    const float* x_rows = (const float*)d_in[0];
    const int*   seeds  = (const int*)d_in[1];
    const float* W1     = (const float*)d_in[2];
    const float* b1     = (const float*)d_in[3];
    const float* W2     = (const float*)d_in[4];
    const float* b2     = (const float*)d_in[5];
    float* out = (float*)d_out;

    int Nrows = in_sizes[0] / D;
    int B = in_sizes[1];

    unsigned short* W1f = (unsigned short*)d_ws;
    unsigned short* W2f = W1f + W1F_ELEMS;

    prep_frags<<<(W1F_ELEMS + W2F_ELEMS + 255) / 256, 256, 0, stream>>>(W1, W2, W1f, W2f);
    rowmlp_kernel<<<B / BM, 256, 0, stream>>>(x_rows, seeds, W1f, b1, W2f, b2, out, Nrows);
}